// Round 5
// baseline (342.751 us; speedup 1.0000x reference)
//
#include <hip/hip_runtime.h>
#include <hip/hip_bf16.h>

// x[16,32,32,32,32] f32, w[32,64,3,3,3] f32, b[64] f32
// ConvTranspose3d(s=2,p=1,k=3) -> (+bias)*0.5 -> maxpool2 -> mean -> clamp[0,1] -> out[16,64]
//
// Window algebra (validated R0/R1, HW-verified again in R10): window w covers conv
// outputs {2w,2w+1}/dim, inputs {w,w+1}/dim. MFMA 16x16x32 bf16: M=16 ww-windows,
// N=16 co, K=32=Cin. Tap->frag rule: (kd,kh,kw) uses frag[dd=(kd==0)][dw=(kw==0)]
// of h-row wh+(kh==0).
//
// R11: wave-fill push (post-mortem: R1/R7 proved LDS+VALU not limiting; R8/R9 proved
// reg-staged pipelining spills; R0's limiter = 2 waves/SIMD with phase-locked pairs):
//  - block = (b, wd, whB): 512 threads / 8 waves, 17-row tile [h17][dd2][w32][ci32]
//    = 69.6 KB LDS -> 2 blocks/CU = 4 waves/SIMD (2x R0's fill).
//  - per-wave code shape IDENTICAL to R0's proven 84-VGPR compile: Bf[27] resident,
//    stage phase disjoint from compute, 8 fresh frag reads + 9-chain burst per window.
//  - wave (c=uw&3, sh=uw>>2): co-tile c, wh-half sh; win order rotated by 4*sh and
//    half order swapped by c&1 to decorrelate same-SIMD wave phases.
//  - ONE barrier per block (tile written once, then read-only; no ring hazards).
//
// ws: [0,4096)B accS[16][64] f32; [4096,...) wB bf16 [cotile4][T27][lane64][j8],
// T in exact consumption order (see TAP tables).

typedef __bf16 bf16x8 __attribute__((ext_vector_type(8)));
typedef float  f32x4  __attribute__((ext_vector_type(4)));
typedef unsigned short ushort_t;
typedef ushort_t ushort4v __attribute__((ext_vector_type(4)));

#define NWIN 29791  // 31^3

__device__ inline ushort_t f2bf(float f) {
    unsigned u = __builtin_bit_cast(unsigned, f);
    u += 0x7FFFu + ((u >> 16) & 1u);   // RNE
    return (ushort_t)(u >> 16);
}

// Consumption-order tap list (kd,kh,kw) for T=0..26
__device__ __constant__ const unsigned char TKD[27] = {2,0,2,0,2,0,2,0, 1,0,1,2,1,0,1,2, 0,1,2,1,0,1,2,1, 0,1,2};
__device__ __constant__ const unsigned char TKH[27] = {0,0,0,0,2,2,2,2, 0,1,0,1,2,1,2,1, 0,1,0,0,2,1,2,2, 1,1,1};
__device__ __constant__ const unsigned char TKW[27] = {0,0,2,2,0,0,2,2, 0,0,2,0,0,2,2,2, 1,0,1,1,1,2,1,1, 1,1,1};

__global__ __launch_bounds__(256) void prep_kernel(const float* __restrict__ w,
                                                   float* __restrict__ ws) {
    int idx = blockIdx.x * 256 + threadIdx.x;
    if (idx < 1024) ws[idx] = 0.f;
    if (idx < 55296) {
        ushort_t* wB = (ushort_t*)((char*)ws + 4096);
        int j = idx & 7;
        int l = (idx >> 3) & 63;
        int q = idx >> 9;           // [0,108) = c*27+T
        int T = q % 27;
        int c = q / 27;
        int ci = ((l >> 4) << 3) + j;
        int co = (c << 4) + (l & 15);
        int k3 = TKD[T] * 9 + TKH[T] * 3 + TKW[T];
        wB[idx] = f2bf(w[(ci * 64 + co) * 27 + k3]);
    }
}

#define MFMA(A, B, C) __builtin_amdgcn_mfma_f32_16x16x32_bf16((A), (B), (C), 0, 0, 0)

// grid = 16 b * 31 wd * 2 whB, 512 threads (8 waves)
__global__ __launch_bounds__(512, 4) void main_kernel(const float* __restrict__ x,
                                                      const float* __restrict__ ws_ro,
                                                      float* __restrict__ accS) {
    __shared__ ushort_t xT[34816];  // [h17][dd2][w32][ci32] bf16; row stride 2048,
                                    // dd stride 1024, w stride 32; ci octets swizzled
                                    // s = oct ^ ((w>>1)&3)

    int bid = blockIdx.x;
    int b   = bid / 62;             // 31*2
    int rr_ = bid - b * 62;
    int wd  = rr_ >> 1;             // [0,31)
    int whB = rr_ & 1;              // wh block half: wh base 16*whB
    int tid = threadIdx.x;
    int lane = tid & 63;
    int wave = tid >> 6;            // 0..7
    int uw   = __builtin_amdgcn_readfirstlane(wave);
    int c    = uw & 3;              // co-tile
    int sh   = uw >> 2;             // wh-half within block (0/1)

    // ---- this wave's 27 weight B-frags (consumption order) -> regs
    const bf16x8* wBv = (const bf16x8*)((const char*)ws_ro + 4096);
    bf16x8 Bf[27];
#pragma unroll
    for (int t = 0; t < 27; ++t) Bf[t] = wBv[(c * 27 + t) * 64 + lane];

    // ---- stage: wave uw stages ci nibble [4uw,4uw+4) for all 17 rows
    {
        int ddl = lane >> 5;
        int wl  = lane & 31;
        int oct = uw >> 1;                       // logical ci octet
        int h2  = uw & 1;                        // half within octet
        int s   = oct ^ ((wl >> 1) & 3);         // swizzled octet slot
        const float* xb = x + (size_t)(b * 32 + uw * 4) * 32768u
                            + (size_t)(wd + ddl) * 1024u + wl;
        ushort_t* dst = &xT[(ddl << 10) + (wl << 5) + (s << 3) + (h2 << 2)];
#pragma unroll
        for (int rr = 0; rr < 17; ++rr) {
            int habs = whB * 16 + rr;
            if (habs > 31) habs = 31;            // garbage row, masked window only
            float v[4];
#pragma unroll
            for (int i = 0; i < 4; ++i) v[i] = xb[(size_t)i * 32768u + habs * 32];
            __hip_bfloat162 p0 = __float22bfloat162_rn(float2{v[0], v[1]});
            __hip_bfloat162 p1 = __float22bfloat162_rn(float2{v[2], v[3]});
            ushort4v pk;
            pk[0] = __builtin_bit_cast(ushort_t, p0.x);
            pk[1] = __builtin_bit_cast(ushort_t, p0.y);
            pk[2] = __builtin_bit_cast(ushort_t, p1.x);
            pk[3] = __builtin_bit_cast(ushort_t, p1.y);
            *(ushort4v*)&dst[rr << 11] = pk;
        }
    }
    __syncthreads();   // tile now read-only; no further barriers

    int m  = lane & 15;
    int kq = lane >> 4;
    float runsum = 0.f;
    const f32x4 Z = (f32x4){0.f, 0.f, 0.f, 0.f};

#pragma unroll
    for (int hh = 0; hh < 2; ++hh) {
        int half = hh ^ (c & 1);               // decorrelate half order across co
        int wbase = half << 4;
        int w0 = wbase + m;                    // <= 31
        int w1 = w0 + 1; if (w1 > 31) w1 = 31; // garbage -> window 31, masked
        int col0 = (w0 << 5) + ((kq ^ ((w0 >> 1) & 3)) << 3);
        int col1 = (w1 << 5) + ((kq ^ ((w1 >> 1) & 3)) << 3);

#pragma unroll
        for (int wi = 0; wi < 8; ++wi) {
            int win = (wi + (sh << 2)) & 7;    // decorrelate win phase across sh
            int r0 = (sh << 3) + win;          // tile row 0..15; +1 <= 16
            int rA = r0 << 11;
            int rB = rA + 2048;

            // FA = row r0 (kh in {1,2}); FB = row r0+1 (kh==0); [dd][dw]
            bf16x8 FA[2][2], FB[2][2];
#pragma unroll
            for (int dd = 0; dd < 2; ++dd) {
                FA[dd][0] = *(const bf16x8*)&xT[rA + (dd << 10) + col0];
                FA[dd][1] = *(const bf16x8*)&xT[rA + (dd << 10) + col1];
                FB[dd][0] = *(const bf16x8*)&xT[rB + (dd << 10) + col0];
                FB[dd][1] = *(const bf16x8*)&xT[rB + (dd << 10) + col1];
            }

            // 27 MFMAs, 9 independent chains, round-robin issue (HW-verified R10)
            f32x4 Ca, Cb, Cc, Cd, Ce, Cf, Cg, Ch, Ci;
            Ca = MFMA(FB[0][1], Bf[0],  Z);   // T0  (2,0,0)
            Cb = MFMA(FB[1][1], Bf[1],  Z);   // T1  (0,0,0)
            Cc = MFMA(FB[0][1], Bf[8],  Z);   // T8  (1,0,0)
            Cd = MFMA(FA[1][1], Bf[9],  Z);   // T9  (0,1,0)
            Ce = MFMA(FB[1][0], Bf[16], Z);   // T16 (0,0,1)
            Cf = MFMA(FA[0][1], Bf[17], Z);   // T17 (1,1,0)
            Cg = MFMA(FB[0][0], Bf[19], Z);   // T19 (1,0,1)
            Ch = MFMA(FA[1][0], Bf[24], Z);   // T24 (0,1,1)
            Ci = MFMA(FA[0][0], Bf[25], Z);   // T25 (1,1,1)
            Ca = MFMA(FB[0][0], Bf[2],  Ca);  // T2  (2,0,2)
            Cb = MFMA(FB[1][0], Bf[3],  Cb);  // T3  (0,0,2)
            Cc = MFMA(FB[0][0], Bf[10], Cc);  // T10 (1,0,2)
            Cd = MFMA(FA[0][1], Bf[11], Cd);  // T11 (2,1,0)
            Ce = MFMA(FB[0][0], Bf[18], Ce);  // T18 (2,0,1)
            Cf = MFMA(FA[0][0], Bf[21], Cf);  // T21 (1,1,2)
            Cg = MFMA(FA[0][0], Bf[23], Cg);  // T23 (1,2,1)
            Ch = MFMA(FA[0][0], Bf[26], Ch);  // T26 (2,1,1)
            Ca = MFMA(FA[0][1], Bf[4],  Ca);  // T4  (2,2,0)
            Cb = MFMA(FA[1][1], Bf[5],  Cb);  // T5  (0,2,0)
            Cc = MFMA(FA[0][1], Bf[12], Cc);  // T12 (1,2,0)
            Cd = MFMA(FA[1][0], Bf[13], Cd);  // T13 (0,1,2)
            Ce = MFMA(FA[1][0], Bf[20], Ce);  // T20 (0,2,1)
            Ca = MFMA(FA[0][0], Bf[6],  Ca);  // T6  (2,2,2)
            Cb = MFMA(FA[1][0], Bf[7],  Cb);  // T7  (0,2,2)
            Cc = MFMA(FA[0][0], Bf[14], Cc);  // T14 (1,2,2)
            Cd = MFMA(FA[0][0], Bf[15], Cd);  // T15 (2,1,2)
            Ce = MFMA(FA[0][0], Bf[22], Ce);  // T22 (2,2,1)

            // single combine: 1 add + max3-shaped tree (8 conv outputs per window)
            f32x4 mx;
#pragma unroll
            for (int i = 0; i < 4; ++i) {
                float s0 = Ca[i] + Cb[i];                       // class (1,1,1) sum
                float m1 = fmaxf(fmaxf(s0, Cc[i]), Cd[i]);      // v_max3
                float m2 = fmaxf(fmaxf(Ce[i], Cf[i]), Cg[i]);   // v_max3
                float m3 = fmaxf(fmaxf(Ch[i], Ci[i]), m1);      // v_max3
                mx[i] = fmaxf(m2, m3);
            }

            // masked accumulate: wh = 16*whB + 8*sh + win, rows ww = wbase+kq*4+rr
            int wh = (whB << 4) + r0;
            if (wh < 31) {
#pragma unroll
                for (int rr = 0; rr < 4; ++rr) {
                    int ww = wbase + (kq << 2) + rr;
                    if (ww < 31) runsum += mx[rr];
                }
            }
        }
    }

    // lanes with same n=(lane&15) hold partials for the same co
    runsum += __shfl_xor(runsum, 16, 64);
    runsum += __shfl_xor(runsum, 32, 64);
    if (lane < 16) atomicAdd(&accS[(b << 6) + (c << 4) + lane], runsum);
}

__global__ __launch_bounds__(256) void finalize_kernel(const float* __restrict__ accS,
                                                       const float* __restrict__ bias,
                                                       float* __restrict__ out) {
    int i = blockIdx.x * 256 + threadIdx.x;
    if (i < 1024) {
        int co = i & 63;
        float v = (accS[i] * (1.f / (float)NWIN) + bias[co]) * 0.5f;
        v = fminf(fmaxf(v, 0.f), 1.f);
        out[i] = v;
    }
}

extern "C" void kernel_launch(void* const* d_in, const int* in_sizes, int n_in,
                              void* d_out, int out_size, void* d_ws, size_t ws_size,
                              hipStream_t stream) {
    const float* x    = (const float*)d_in[0];
    const float* w    = (const float*)d_in[1];
    const float* bias = (const float*)d_in[2];
    float* out = (float*)d_out;
    float* ws  = (float*)d_ws;

    prep_kernel<<<216, 256, 0, stream>>>(w, ws);
    main_kernel<<<16 * 31 * 2, 512, 0, stream>>>(x, ws, ws);
    finalize_kernel<<<4, 256, 0, stream>>>(ws, bias, out);
}

// Round 6
// 135.188 us; speedup vs baseline: 2.5354x; 2.5354x over previous
//
#include <hip/hip_runtime.h>
#include <hip/hip_bf16.h>

// x[16,32,32,32,32] f32, w[32,64,3,3,3] f32, b[64] f32
// ConvTranspose3d(s=2,p=1,k=3) -> (+bias)*0.5 -> maxpool2 -> mean -> clamp[0,1] -> out[16,64]
//
// Window algebra (validated R0/R1, HW re-verified R10): window w covers conv outputs
// {2w,2w+1}/dim, inputs {w,w+1}/dim. MFMA 16x16x32 bf16: M=16 ww-windows, N=16 co,
// K=32=Cin. Tap->frag rule: (kd,kh,kw) uses frag[dd=(kd==0)][dw=(kw==0)] of row
// wh+(kh==0).
//
// R12: deferred-combine software pipeline on R0's register-safe shell.
// Post-mortems: R8/R9/R11 all spilled (Bf[27]-resident needs the full 2-wave/SIMD
// 256-reg budget -> occupancy is structurally 2 waves/SIMD; never reg-stage across
// pinned regions). R0 model closes as: lockstep waves, serial stream = 44% MFMA +
// 36% VALU + LDS + waits; per-window combine drains serialize MFMA issue.
// Fix: banks P/Q hold window n's 9 accs; program order per window n+1:
//   [F-reads(n+1)] [combine(n) - operands 400+ cyc old, also hides ds_read latency]
//   [27-MFMA burst(n+1)]
// -> wave stream is gap-free MFMA with VALU in issue gaps. Also: unconditional
// sumv += mx per window, ww-mask applied ONCE at end (-12 VALU/window).
//
// ws: [0,4096)B accS[16][64] f32; [4096,...) wB bf16 [cotile4][T27][lane64][j8],
// T in exact consumption order (see TAP tables).

typedef __bf16 bf16x8 __attribute__((ext_vector_type(8)));
typedef float  f32x4  __attribute__((ext_vector_type(4)));
typedef unsigned short ushort_t;
typedef ushort_t ushort8 __attribute__((ext_vector_type(8)));

#define NWIN 29791  // 31^3

__device__ inline ushort_t f2bf(float f) {
    unsigned u = __builtin_bit_cast(unsigned, f);
    u += 0x7FFFu + ((u >> 16) & 1u);   // RNE
    return (ushort_t)(u >> 16);
}

// Consumption-order tap list (kd,kh,kw) for T=0..26
__device__ __constant__ const unsigned char TKD[27] = {2,0,2,0,2,0,2,0, 1,0,1,2,1,0,1,2, 0,1,2,1,0,1,2,1, 0,1,2};
__device__ __constant__ const unsigned char TKH[27] = {0,0,0,0,2,2,2,2, 0,1,0,1,2,1,2,1, 0,1,0,0,2,1,2,2, 1,1,1};
__device__ __constant__ const unsigned char TKW[27] = {0,0,2,2,0,0,2,2, 0,0,2,0,0,2,2,2, 1,0,1,1,1,2,1,1, 1,1,1};

__global__ __launch_bounds__(256) void prep_kernel(const float* __restrict__ w,
                                                   float* __restrict__ ws) {
    int idx = blockIdx.x * 256 + threadIdx.x;
    if (idx < 1024) ws[idx] = 0.f;
    if (idx < 55296) {
        ushort_t* wB = (ushort_t*)((char*)ws + 4096);
        int j = idx & 7;
        int l = (idx >> 3) & 63;
        int q = idx >> 9;           // [0,108) = c*27+T
        int T = q % 27;
        int c = q / 27;
        int ci = ((l >> 4) << 3) + j;
        int co = (c << 4) + (l & 15);
        int k3 = TKD[T] * 9 + TKH[T] * 3 + TKW[T];
        wB[idx] = f2bf(w[(ci * 64 + co) * 27 + k3]);
    }
}

#define MFMA(A, B, C) __builtin_amdgcn_mfma_f32_16x16x32_bf16((A), (B), (C), 0, 0, 0)

// grid = 16 b * 31 wd * 4 whg, 256 threads (R0 shell)
__global__ __launch_bounds__(256, 2) void main_kernel(const float* __restrict__ x,
                                                      const float* __restrict__ ws_ro,
                                                      float* __restrict__ accS) {
    __shared__ ushort_t xT[18432];  // [dd2][hh9][w32][ci32] bf16, s = kq ^ ((w>>1)&3)

    int bid = blockIdx.x;
    int b   = bid / 124;            // 31*4
    int r   = bid - b * 124;
    int wd  = r >> 2;               // [0,31)
    int whg = r & 3;                // wh group of 8
    int tid = threadIdx.x;
    int lane = tid & 63;
    int wave = tid >> 6;
    int uw   = __builtin_amdgcn_readfirstlane(wave);

    // ---- this wave's 27 weight B-frags (consumption order) -> regs
    const bf16x8* wBv = (const bf16x8*)((const char*)ws_ro + 4096);
    bf16x8 Bf[27];
#pragma unroll
    for (int t = 0; t < 27; ++t) Bf[t] = wBv[(uw * 27 + t) * 64 + lane];

    // ---- stage: wave uw stages ci planes [8uw,8uw+8); lane = (dd=lane>>5, w=lane&31)
    {
        int dd = lane >> 5;
        int wl = lane & 31;
        const float* xb = x + ((size_t)(b * 32 + uw * 8)) * 32768u
                            + ((size_t)(wd + 1) << 10) + ((size_t)(whg << 3) << 5);
        int voff = (dd - 1) * 1024 + wl;
        int ro8  = (whg == 3) ? 7 * 32 : 8 * 32;          // clamped last row (masked window only)
        int s    = uw ^ ((wl >> 1) & 3);
        ushort_t* dst = &xT[((dd * 9) << 10) + (wl << 5) + (s << 3)];
#pragma unroll
        for (int rr = 0; rr < 9; ++rr) {
            int ro = (rr < 8) ? rr * 32 : ro8;
            float v[8];
#pragma unroll
            for (int i = 0; i < 8; ++i) v[i] = xb[(size_t)i * 32768u + voff + ro];
            ushort8 pk;
#pragma unroll
            for (int i = 0; i < 4; ++i) {
                __hip_bfloat162 p2 = __float22bfloat162_rn(float2{v[2 * i], v[2 * i + 1]});
                pk[2 * i]     = __builtin_bit_cast(ushort_t, p2.x);
                pk[2 * i + 1] = __builtin_bit_cast(ushort_t, p2.y);
            }
            *(ushort8*)&dst[rr << 10] = pk;
        }
    }
    __syncthreads();

    int m  = lane & 15;
    int kq = lane >> 4;
    const f32x4 Z = (f32x4){0.f, 0.f, 0.f, 0.f};

    // 27-MFMA burst into bank C[9] (mapping HW-verified R10)
    auto burst = [&](f32x4* C, const bf16x8 FA[2][2], const bf16x8 FB[2][2]) {
        C[0] = MFMA(FB[0][1], Bf[0],  Z);     // T0  (2,0,0)
        C[1] = MFMA(FB[1][1], Bf[1],  Z);     // T1  (0,0,0)
        C[2] = MFMA(FB[0][1], Bf[8],  Z);     // T8  (1,0,0)
        C[3] = MFMA(FA[1][1], Bf[9],  Z);     // T9  (0,1,0)
        C[4] = MFMA(FB[1][0], Bf[16], Z);     // T16 (0,0,1)
        C[5] = MFMA(FA[0][1], Bf[17], Z);     // T17 (1,1,0)
        C[6] = MFMA(FB[0][0], Bf[19], Z);     // T19 (1,0,1)
        C[7] = MFMA(FA[1][0], Bf[24], Z);     // T24 (0,1,1)
        C[8] = MFMA(FA[0][0], Bf[25], Z);     // T25 (1,1,1)
        C[0] = MFMA(FB[0][0], Bf[2],  C[0]);  // T2  (2,0,2)
        C[1] = MFMA(FB[1][0], Bf[3],  C[1]);  // T3  (0,0,2)
        C[2] = MFMA(FB[0][0], Bf[10], C[2]);  // T10 (1,0,2)
        C[3] = MFMA(FA[0][1], Bf[11], C[3]);  // T11 (2,1,0)
        C[4] = MFMA(FB[0][0], Bf[18], C[4]);  // T18 (2,0,1)
        C[5] = MFMA(FA[0][0], Bf[21], C[5]);  // T21 (1,1,2)
        C[6] = MFMA(FA[0][0], Bf[23], C[6]);  // T23 (1,2,1)
        C[7] = MFMA(FA[0][0], Bf[26], C[7]);  // T26 (2,1,1)
        C[0] = MFMA(FA[0][1], Bf[4],  C[0]);  // T4  (2,2,0)
        C[1] = MFMA(FA[1][1], Bf[5],  C[1]);  // T5  (0,2,0)
        C[2] = MFMA(FA[0][1], Bf[12], C[2]);  // T12 (1,2,0)
        C[3] = MFMA(FA[1][0], Bf[13], C[3]);  // T13 (0,1,2)
        C[4] = MFMA(FA[1][0], Bf[20], C[4]);  // T20 (0,2,1)
        C[0] = MFMA(FA[0][0], Bf[6],  C[0]);  // T6  (2,2,2)
        C[1] = MFMA(FA[1][0], Bf[7],  C[1]);  // T7  (0,2,2)
        C[2] = MFMA(FA[0][0], Bf[14], C[2]);  // T14 (1,2,2)
        C[3] = MFMA(FA[0][0], Bf[15], C[3]);  // T15 (2,1,2)
        C[4] = MFMA(FA[0][0], Bf[22], C[4]);  // T22 (2,2,1)
    };

    f32x4 sumv0 = Z, sumv1 = Z;     // per-half window sums; ww-mask applied at end

    // combine window cidx (0..15): max over 8 conv outputs, unconditional sumv add
    auto combine = [&](const f32x4* C, int cidx) {
        int wh = (whg << 3) + (cidx & 7);
        if (wh < 31) {                               // uniform (false only whg=3,win=7)
            f32x4& sv = (cidx < 8) ? sumv0 : sumv1;  // static under full unroll
#pragma unroll
            for (int i = 0; i < 4; ++i) {
                float s0 = C[0][i] + C[1][i];                      // class (1,1,1) sum
                float m1 = fmaxf(fmaxf(s0, C[2][i]), C[3][i]);     // v_max3
                float m2 = fmaxf(fmaxf(C[4][i], C[5][i]), C[6][i]);// v_max3
                float m3 = fmaxf(fmaxf(C[7][i], C[8][i]), m1);     // v_max3
                sv[i] += fmaxf(m2, m3);
            }
        }
    };

    f32x4 P[9], Q[9];               // double-banked accumulators (static indices only)

#pragma unroll
    for (int half = 0; half < 2; ++half) {
        int wbase = half << 4;
        int w0 = wbase + m;                    // <= 31
        int w1 = w0 + 1; if (w1 > 31) w1 = 31; // garbage -> window 31, masked at end
        int col0 = (w0 << 5) + ((kq ^ ((w0 >> 1) & 3)) << 3);
        int col1 = (w1 << 5) + ((kq ^ ((w1 >> 1) & 3)) << 3);

#pragma unroll
        for (int win = 0; win < 8; ++win) {
            int idx = half * 8 + win;          // 0..15, compile-time under unroll

            // F-reads for THIS window (issued before prev combine -> latency hidden)
            bf16x8 FA[2][2], FB[2][2];
#pragma unroll
            for (int dd = 0; dd < 2; ++dd) {
                int rowA = (dd * 9 + win) << 10;
                int rowB = (dd * 9 + win + 1) << 10;
                FA[dd][0] = *(const bf16x8*)&xT[rowA + col0];
                FA[dd][1] = *(const bf16x8*)&xT[rowA + col1];
                FB[dd][0] = *(const bf16x8*)&xT[rowB + col0];
                FB[dd][1] = *(const bf16x8*)&xT[rowB + col1];
            }

            // deferred combine of previous window (operands long ready)
            if (idx > 0) combine(((idx - 1) & 1) ? Q : P, idx - 1);

            // MFMA burst for this window
            burst((idx & 1) ? Q : P, FA, FB);
        }
    }
    combine(Q, 15);   // idx 15 is odd -> bank Q

    // end-mask: half-0 rows ww=0..15 all valid; half-1 row rr=3 invalid iff kq==3 (ww=31)
    float runsum = sumv0[0] + sumv0[1] + sumv0[2] + sumv0[3]
                 + sumv1[0] + sumv1[1] + sumv1[2]
                 + ((kq == 3) ? 0.f : sumv1[3]);

    // lanes with same n=(lane&15) hold partials for the same co
    runsum += __shfl_xor(runsum, 16, 64);
    runsum += __shfl_xor(runsum, 32, 64);
    if (lane < 16) atomicAdd(&accS[(b << 6) + (wave << 4) + lane], runsum);
}

__global__ __launch_bounds__(256) void finalize_kernel(const float* __restrict__ accS,
                                                       const float* __restrict__ bias,
                                                       float* __restrict__ out) {
    int i = blockIdx.x * 256 + threadIdx.x;
    if (i < 1024) {
        int co = i & 63;
        float v = (accS[i] * (1.f / (float)NWIN) + bias[co]) * 0.5f;
        v = fminf(fmaxf(v, 0.f), 1.f);
        out[i] = v;
    }
}

extern "C" void kernel_launch(void* const* d_in, const int* in_sizes, int n_in,
                              void* d_out, int out_size, void* d_ws, size_t ws_size,
                              hipStream_t stream) {
    const float* x    = (const float*)d_in[0];
    const float* w    = (const float*)d_in[1];
    const float* bias = (const float*)d_in[2];
    float* out = (float*)d_out;
    float* ws  = (float*)d_ws;

    prep_kernel<<<216, 256, 0, stream>>>(w, ws);
    main_kernel<<<16 * 31 * 4, 256, 0, stream>>>(x, ws, ws);
    finalize_kernel<<<4, 256, 0, stream>>>(ws, bias, out);
}